// Round 5
// baseline (4638.870 us; speedup 1.0000x reference)
//
#include <hip/hip_runtime.h>
#include <math.h>

#define Lt 512   // timesteps
#define Bn 128   // batch
#define Dd 512   // input dim
#define Hh 512   // hidden dim
#define BH (Bn * Hh)

typedef __attribute__((ext_vector_type(4))) float f32x4;
typedef __attribute__((ext_vector_type(8))) __bf16 bf16x8;
typedef __attribute__((ext_vector_type(8))) unsigned short u16x8;
typedef __attribute__((ext_vector_type(4))) unsigned int u32x4;

#define MFMA16 __builtin_amdgcn_mfma_f32_16x16x32_bf16

__device__ __forceinline__ float bf2f(unsigned short s) {
    return __uint_as_float(((unsigned)s) << 16);
}
__device__ __forceinline__ unsigned short f2bf_rne(float f) {
    unsigned u = __float_as_uint(f);
    u = (u + 0x7FFFu + ((u >> 16) & 1u)) >> 16;
    return (unsigned short)u;
}
// tanh via hw exp+rcp; saturates exactly at +/-1, NaN-free
__device__ __forceinline__ float tanh_fast(float z) {
    float e = __expf(2.f * z);
    return 1.f - 2.f * __builtin_amdgcn_rcpf(e + 1.f);
}
// result = (top16(b)<<16) | top16(a)
__device__ __forceinline__ unsigned pack_hi16(unsigned a, unsigned b) {
    return __builtin_amdgcn_perm(b, a, 0x07060302u);
}
// result = (low16(b)<<16) | low16(a)
__device__ __forceinline__ unsigned pack_lo16(unsigned a, unsigned b) {
    return __builtin_amdgcn_perm(b, a, 0x05040100u);
}
// XOR-swizzled LDS index (u16 units) for a [16][512] u16 tile (xproj).
__device__ __forceinline__ int swzi(int r_, int k_) {
    return (r_ << 9) + (k_ ^ ((r_ & 7) << 3));
}

__global__ void zero_flags_kernel(unsigned* __restrict__ flags) {
    int i = threadIdx.x;
    if (i < 128) flags[i] = 0u;
}

// Preload one wave's 16-row W j-slice as bf16 hi/lo MFMA B-fragments into
// VGPRs: wH[c]/wL[c] hold W[row][c*32+quad*8 .. +8]. 128 VGPRs per tile.
__device__ __forceinline__ void preload_w(const float* __restrict__ W, int row,
                                          int quad, bf16x8* wH, bf16x8* wL) {
    const float* wr = W + (size_t)row * 512;
    #pragma unroll
    for (int c = 0; c < 16; ++c) {
        int kk = c * 32 + quad * 8;
        float4 v0 = *(const float4*)(wr + kk);
        float4 v1 = *(const float4*)(wr + kk + 4);
        float vv[8] = {v0.x, v0.y, v0.z, v0.w, v1.x, v1.y, v1.z, v1.w};
        u16x8 hh, ll;
        #pragma unroll
        for (int e = 0; e < 8; ++e) {
            unsigned short s = f2bf_rne(vv[e]);
            hh[e] = s;
            ll[e] = f2bf_rne(vv[e] - bf2f(s));
        }
        wH[c] = __builtin_bit_cast(bf16x8, hh);
        wL[c] = __builtin_bit_cast(bf16x8, ll);
    }
}

// ---------------------------------------------------------------------------
// Kernel 1 (unchanged, verified R2): xproj = x . Wx^T + bx + bh into
// out[0 .. L*B*H). 512 wgs x 256 thr; Wx fragments in VGPRs, x staged once
// per wg into swizzled LDS hi/lo shared by 4 waves.
// ---------------------------------------------------------------------------
__global__ __launch_bounds__(256, 2) void xproj_kernel(
    const float* __restrict__ x, const float* __restrict__ Wx,
    const float* __restrict__ bx, const float* __restrict__ bh,
    float* __restrict__ out) {

    __shared__ unsigned short XH[16 * 512], XL[16 * 512];

    const int tid = threadIdx.x;
    const int wave = tid >> 6;
    const int lane = tid & 63;
    const int rw = lane & 15;
    const int quad = (lane >> 4) & 3;
    const int jgrp = blockIdx.x >> 6;   // 0..7
    const int mslab = blockIdx.x & 63;  // 0..63
    const int j0 = (jgrp * 4 + wave) * 16;

    bf16x8 wxH[16], wxL[16];
    preload_w(Wx, j0 + rw, quad, wxH, wxL);
    const float bsum = bx[j0 + rw] + bh[j0 + rw];

    const int r = tid >> 4;           // 0..15: staged row
    const int cf0 = (tid & 15) * 32;  // 32-float column chunk

    for (int it = 0; it < 64; ++it) {
        const int m0 = mslab * 1024 + it * 16;
        {
            const float* xr = x + (size_t)(m0 + r) * Dd + cf0;
            float4 v[8];
            #pragma unroll
            for (int q = 0; q < 8; ++q) v[q] = *(const float4*)(xr + q * 4);
            #pragma unroll
            for (int g = 0; g < 4; ++g) {
                float4 va = v[2 * g], vb = v[2 * g + 1];
                unsigned ua0 = __float_as_uint(va.x), ua1 = __float_as_uint(va.y);
                unsigned ua2 = __float_as_uint(va.z), ua3 = __float_as_uint(va.w);
                unsigned ub0 = __float_as_uint(vb.x), ub1 = __float_as_uint(vb.y);
                unsigned ub2 = __float_as_uint(vb.z), ub3 = __float_as_uint(vb.w);
                u32x4 Hq = {pack_hi16(ua0, ua1), pack_hi16(ua2, ua3),
                            pack_hi16(ub0, ub1), pack_hi16(ub2, ub3)};
                float l0 = va.x - __uint_as_float(ua0 & 0xFFFF0000u);
                float l1 = va.y - __uint_as_float(ua1 & 0xFFFF0000u);
                float l2 = va.z - __uint_as_float(ua2 & 0xFFFF0000u);
                float l3 = va.w - __uint_as_float(ua3 & 0xFFFF0000u);
                float l4 = vb.x - __uint_as_float(ub0 & 0xFFFF0000u);
                float l5 = vb.y - __uint_as_float(ub1 & 0xFFFF0000u);
                float l6 = vb.z - __uint_as_float(ub2 & 0xFFFF0000u);
                float l7 = vb.w - __uint_as_float(ub3 & 0xFFFF0000u);
                u32x4 Lq = {pack_hi16(__float_as_uint(l0), __float_as_uint(l1)),
                            pack_hi16(__float_as_uint(l2), __float_as_uint(l3)),
                            pack_hi16(__float_as_uint(l4), __float_as_uint(l5)),
                            pack_hi16(__float_as_uint(l6), __float_as_uint(l7))};
                int idx = swzi(r, cf0 + g * 8);
                *(u32x4*)&XH[idx] = Hq;
                *(u32x4*)&XL[idx] = Lq;
            }
        }
        __syncthreads();
        f32x4 aHH = {0.f, 0.f, 0.f, 0.f};
        f32x4 aHL = {0.f, 0.f, 0.f, 0.f};
        f32x4 aLH = {0.f, 0.f, 0.f, 0.f};
        #pragma unroll
        for (int c = 0; c < 16; ++c) {
            int kk = c * 32 + quad * 8;
            bf16x8 aH = __builtin_bit_cast(bf16x8, *(const u16x8*)&XH[swzi(rw, kk)]);
            bf16x8 aL = __builtin_bit_cast(bf16x8, *(const u16x8*)&XL[swzi(rw, kk)]);
            aHH = MFMA16(aH, wxH[c], aHH, 0, 0, 0);
            aHL = MFMA16(aH, wxL[c], aHL, 0, 0, 0);
            aLH = MFMA16(aL, wxH[c], aLH, 0, 0, 0);
        }
        f32x4 acc = aHH + aHL + aLH;
        #pragma unroll
        for (int rr = 0; rr < 4; ++rr) {
            int m = m0 + quad * 4 + rr;
            out[(size_t)m * Hh + (j0 + rw)] = acc[rr] + bsum;
        }
        __syncthreads();
    }
}

// ---------------------------------------------------------------------------
// Kernel 2: recurrence — R1's VERIFIED 1-wave agent-scope protocol, re-tiled
// to 128 wgs x 64 thr. wg = (bg = blk&7, jg2 = blk>>3, 0..15); the wave owns
// TWO j-tiles jA = jg2*32, jB = jA+16 (Wh hi/lo fragments in 256 VGPRs).
// Ring per bg: 16 producers (was 32) -> smaller convoy max, 16 flags in one
// cacheline, 4 MB/step IC pull (was 8). No barriers, no LDS on the chain.
// Per step: poll 16 flags -> h pull (u64 agent loads) + unpack (shared A
// fragments) -> 16 c-steps x 6 MFMA -> tanh(acc+xp) -> publish packed u32
// (agent) -> vmcnt(0) -> flag -> out stores + xp prefetch for t+1 (both off
// the critical path). Deadlock-free: 128 single-wave wgs always co-resident
// (<= 4 waves/CU even at max VGPR).
// ---------------------------------------------------------------------------
__global__ __launch_bounds__(64, 1) void rnn_rec2j_kernel(
    const float* __restrict__ h0in, const float* __restrict__ Wh,
    float* __restrict__ out, unsigned* __restrict__ hpk,
    unsigned* __restrict__ flags) {

    const int lane = threadIdx.x;
    const int bg = blockIdx.x & 7;      // same bg -> same XCD under rr dispatch
    const int jg2 = blockIdx.x >> 3;    // 0..15
    const int b0 = bg * 16;
    const int rw = lane & 15;
    const int quad = lane >> 4;
    const int jA = jg2 * 32;
    const int jB = jA + 16;

    bf16x8 wAH[16], wAL[16], wBH[16], wBL[16];
    preload_w(Wh, jA + rw, quad, wAH, wAL);
    preload_w(Wh, jB + rw, quad, wBH, wBL);

    unsigned* myflag = flags + bg * 16 + jg2;

    // ---- prologue: publish h0 tile into buf1 (read by step 0) ----
    #pragma unroll
    for (int rr = 0; rr < 4; ++rr) {
        int b = b0 + quad * 4 + rr;
        {
            float v = h0in[(size_t)b * Hh + (jA + rw)];
            unsigned u = __float_as_uint(v);
            unsigned hb = u >> 16;  // trunc split
            unsigned lb = __float_as_uint(v - __uint_as_float(u & 0xFFFF0000u)) >> 16;
            __hip_atomic_store(hpk + BH + (size_t)b * Hh + (jA + rw),
                               (hb << 16) | lb, __ATOMIC_RELAXED,
                               __HIP_MEMORY_SCOPE_AGENT);
        }
        {
            float v = h0in[(size_t)b * Hh + (jB + rw)];
            unsigned u = __float_as_uint(v);
            unsigned hb = u >> 16;
            unsigned lb = __float_as_uint(v - __uint_as_float(u & 0xFFFF0000u)) >> 16;
            __hip_atomic_store(hpk + BH + (size_t)b * Hh + (jB + rw),
                               (hb << 16) | lb, __ATOMIC_RELAXED,
                               __HIP_MEMORY_SCOPE_AGENT);
        }
    }
    asm volatile("s_waitcnt vmcnt(0)" ::: "memory");
    if (lane == 0) {
        __hip_atomic_store(myflag, 1u, __ATOMIC_RELAXED,
                           __HIP_MEMORY_SCOPE_AGENT);
    }

    // xp prefetch for step 0 (in flight during the step-0 poll)
    float xpA[4], xpB[4];
    {
        const float* xr = out;  // t = 0
        #pragma unroll
        for (int rr = 0; rr < 4; ++rr) {
            int b = b0 + quad * 4 + rr;
            xpA[rr] = xr[(size_t)b * Hh + (jA + rw)];
            xpB[rr] = xr[(size_t)b * Hh + (jB + rw)];
        }
    }

    for (int t = 0; t < Lt; ++t) {
        // ---- wait for h_{t-1}: the 16 producer wgs of this bg ----
        {
            const unsigned tgt = (unsigned)t + 1u;
            const unsigned* fp = flags + bg * 16 + (lane & 15);
            while (true) {
                unsigned v = __hip_atomic_load(fp, __ATOMIC_RELAXED,
                                               __HIP_MEMORY_SCOPE_AGENT);
                if (__ballot(v >= tgt) == 0xFFFFFFFFFFFFFFFFull) break;
            }
        }

        // ---- h phase: h_{t-1} * Wh^T, two output j-tiles ----
        f32x4 aAHH = {0.f, 0.f, 0.f, 0.f};
        f32x4 aAHL = {0.f, 0.f, 0.f, 0.f};
        f32x4 aALH = {0.f, 0.f, 0.f, 0.f};
        f32x4 aBHH = {0.f, 0.f, 0.f, 0.f};
        f32x4 aBHL = {0.f, 0.f, 0.f, 0.f};
        f32x4 aBLH = {0.f, 0.f, 0.f, 0.f};
        const unsigned* hrow =
            hpk + (size_t)((t + 1) & 1) * BH + (size_t)(b0 + rw) * Hh;
        #pragma unroll
        for (int c = 0; c < 16; ++c) {
            int kk = c * 32 + quad * 8;
            unsigned long long p0 = __hip_atomic_load(
                (const unsigned long long*)(hrow + kk + 0),
                __ATOMIC_RELAXED, __HIP_MEMORY_SCOPE_AGENT);
            unsigned long long p1 = __hip_atomic_load(
                (const unsigned long long*)(hrow + kk + 2),
                __ATOMIC_RELAXED, __HIP_MEMORY_SCOPE_AGENT);
            unsigned long long p2 = __hip_atomic_load(
                (const unsigned long long*)(hrow + kk + 4),
                __ATOMIC_RELAXED, __HIP_MEMORY_SCOPE_AGENT);
            unsigned long long p3 = __hip_atomic_load(
                (const unsigned long long*)(hrow + kk + 6),
                __ATOMIC_RELAXED, __HIP_MEMORY_SCOPE_AGENT);
            unsigned q0 = (unsigned)p0, q1 = (unsigned)(p0 >> 32);
            unsigned q2 = (unsigned)p1, q3 = (unsigned)(p1 >> 32);
            unsigned q4 = (unsigned)p2, q5 = (unsigned)(p2 >> 32);
            unsigned q6 = (unsigned)p3, q7 = (unsigned)(p3 >> 32);
            u32x4 hi4 = {pack_hi16(q0, q1), pack_hi16(q2, q3),
                         pack_hi16(q4, q5), pack_hi16(q6, q7)};
            u32x4 lo4 = {pack_lo16(q0, q1), pack_lo16(q2, q3),
                         pack_lo16(q4, q5), pack_lo16(q6, q7)};
            bf16x8 aH = __builtin_bit_cast(bf16x8, hi4);
            bf16x8 aL = __builtin_bit_cast(bf16x8, lo4);
            aAHH = MFMA16(aH, wAH[c], aAHH, 0, 0, 0);
            aAHL = MFMA16(aH, wAL[c], aAHL, 0, 0, 0);
            aALH = MFMA16(aL, wAH[c], aALH, 0, 0, 0);
            aBHH = MFMA16(aH, wBH[c], aBHH, 0, 0, 0);
            aBHL = MFMA16(aH, wBL[c], aBHL, 0, 0, 0);
            aBLH = MFMA16(aL, wBH[c], aBLH, 0, 0, 0);
        }
        f32x4 accA = aAHH + aAHL + aALH;
        f32x4 accB = aBHH + aBHL + aBLH;

        // ---- epilogue: C/D layout col=lane&15 (j), row=quad*4+rr (b) ----
        float hvA[4], hvB[4];
        #pragma unroll
        for (int rr = 0; rr < 4; ++rr) {
            hvA[rr] = tanh_fast(accA[rr] + xpA[rr]);
            hvB[rr] = tanh_fast(accB[rr] + xpB[rr]);
        }

        unsigned* hw = hpk + (size_t)(t & 1) * BH;
        #pragma unroll
        for (int rr = 0; rr < 4; ++rr) {
            int b = b0 + quad * 4 + rr;
            {
                unsigned u = __float_as_uint(hvA[rr]);
                unsigned hb = u >> 16;
                unsigned lb = __float_as_uint(hvA[rr] -
                                __uint_as_float(u & 0xFFFF0000u)) >> 16;
                __hip_atomic_store(hw + (size_t)b * Hh + (jA + rw),
                                   (hb << 16) | lb, __ATOMIC_RELAXED,
                                   __HIP_MEMORY_SCOPE_AGENT);
            }
            {
                unsigned u = __float_as_uint(hvB[rr]);
                unsigned hb = u >> 16;
                unsigned lb = __float_as_uint(hvB[rr] -
                                __uint_as_float(u & 0xFFFF0000u)) >> 16;
                __hip_atomic_store(hw + (size_t)b * Hh + (jB + rw),
                                   (hb << 16) | lb, __ATOMIC_RELAXED,
                                   __HIP_MEMORY_SCOPE_AGENT);
            }
        }
        asm volatile("s_waitcnt vmcnt(0)" ::: "memory");
        if (lane == 0 && t + 1 < Lt) {
            __hip_atomic_store(myflag, (unsigned)(t + 2), __ATOMIC_RELAXED,
                               __HIP_MEMORY_SCOPE_AGENT);
        }

        // ---- off the critical path: out stores + xp prefetch for t+1 ----
        #pragma unroll
        for (int rr = 0; rr < 4; ++rr) {
            int b = b0 + quad * 4 + rr;
            out[((size_t)t * Bn + b) * Hh + (jA + rw)] = hvA[rr];
            out[((size_t)t * Bn + b) * Hh + (jB + rw)] = hvB[rr];
        }
        if (t + 1 < Lt) {
            const float* xr = out + (size_t)(t + 1) * BH;
            #pragma unroll
            for (int rr = 0; rr < 4; ++rr) {
                int b = b0 + quad * 4 + rr;
                xpA[rr] = xr[(size_t)b * Hh + (jA + rw)];
                xpB[rr] = xr[(size_t)b * Hh + (jB + rw)];
            }
        } else {
            #pragma unroll
            for (int rr = 0; rr < 4; ++rr) {
                int b = b0 + quad * 4 + rr;
                out[(size_t)Lt * BH + (size_t)b * Hh + (jA + rw)] = hvA[rr];
                out[(size_t)Lt * BH + (size_t)b * Hh + (jB + rw)] = hvB[rr];
            }
        }
    }
}

extern "C" void kernel_launch(void* const* d_in, const int* in_sizes, int n_in,
                              void* d_out, int out_size, void* d_ws, size_t ws_size,
                              hipStream_t stream) {
    const float* x    = (const float*)d_in[0];  // [L,B,D]
    const float* h0   = (const float*)d_in[1];  // [B,H]
    const float* Wx_w = (const float*)d_in[2];  // [H,D]
    const float* Wx_b = (const float*)d_in[3];  // [H]
    const float* Wh_w = (const float*)d_in[4];  // [H,H]
    const float* Wh_b = (const float*)d_in[5];  // [H]
    float* out = (float*)d_out;                 // hAll [L,B,H] ++ h_last [B,H]

    unsigned* hpk   = (unsigned*)d_ws;          // 2 x [B][H] packed (hi|lo), 512 KB
    unsigned* flags = hpk + 2 * BH;             // [8][16] monotonic counters

    zero_flags_kernel<<<1, 128, 0, stream>>>(flags);
    // Pass 1: xproj (+ both biases) into out[0 .. L*B*H)
    xproj_kernel<<<512, 256, 0, stream>>>(x, Wx_w, Wx_b, Wh_b, out);
    // Pass 2: recurrence, reads xp from out and overwrites with h_t
    rnn_rec2j_kernel<<<128, 64, 0, stream>>>(h0, Wh_w, out, hpk, flags);
}